// Round 12
// baseline (128.334 us; speedup 1.0000x reference)
//
#include <hip/hip_runtime.h>
#include <hip/hip_fp16.h>

// BackProjectionLinear: out[b,p] = sum_d apod[d] * lerp(sino[b,d], k[p,d], a[p,d]) / 63.5
// B=4, N_DET=128, N_T=2048, pixels=65536.
//
// R12: R4/R8/R10/R11 all pin at 43-49us regardless of phase count, thread
// count, occupancy, or staging format -> the invariant is the barrier-locked
// LDS staging discipline itself. Since R10 the gather source (ws16, 2MB
// packed fp16) fits in every XCD's 4MB L2 -- LDS staging buys nothing.
// Drop it: barrier-free kernel, gathers straight from L2.
//  - cvt pre-pack (R10): ws16[det][t] = 4 batches fp16 in 8B.
//  - bp: 256-thr blocks, no LDS, no __syncthreads. Thread = 1 px x 8 dets:
//    4 lut float4 (the 64B line, read once) -> 16 independent uint2 L2
//    gathers -> 4 atomicAdd. Two dependent memory epochs total; TLP and
//    MLP do the latency hiding (4096 blocks, ~45 VGPR, no LDS -> up to
//    32 waves/CU).
//  - octet = bid&15 (bid%8 ~ XCD): each XCD's L2 holds all of ws16 (2MB).
//  - atomics into zeroed out (R9: atomics == stores, not a limiter).

#define NB      4
#define NDET    128
#define NT      2048
#define NPIX    65536
#define DBLOCK  8
#define THREADS 256

// ---- pass 1: sino fp32[4][128][2048] -> ws16[det][t] = (h0,h1,h2,h3) 8B ----
__global__ __launch_bounds__(256)
void cvt_kernel(const float* __restrict__ sino, uint2* __restrict__ ws16) {
    const int id = blockIdx.x * 256 + threadIdx.x;     // det*NT + t
    float v0 = sino[id];
    float v1 = sino[id + NDET * NT];
    float v2 = sino[id + 2 * NDET * NT];
    float v3 = sino[id + 3 * NDET * NT];
    __half2 h01 = __floats2half2_rn(v0, v1);
    __half2 h23 = __floats2half2_rn(v2, v3);
    uint2 u;
    u.x = *(const unsigned*)&h01;
    u.y = *(const unsigned*)&h23;
    ws16[id] = u;
}

__global__ __launch_bounds__(THREADS, 4)
void bp_kernel(const uint2* __restrict__ ws16,
               const float* __restrict__ lut,
               float* __restrict__ out) {
    const int tid   = threadIdx.x;
    const int octet = blockIdx.x & 15;   // bid%8 ~ XCD: ws16 L2-resident
    const int px    = (blockIdx.x >> 4) * THREADS + tid;
    const int d0    = octet * DBLOCK;

    float apod[DBLOCK];
#pragma unroll
    for (int j = 0; j < DBLOCK; ++j) {
        float x = (float)(d0 + j) * (6.28318530717958647692f / 127.0f);
        apod[j] = 0.5f - 0.5f * __cosf(x);
    }

    // ---- the pixel's 64B lut line: 4 independent float4 loads ----
    const float4* lp = (const float4*)(lut + ((size_t)px * NDET + d0) * 2);
    float4 L[4];
#pragma unroll
    for (int q = 0; q < 4; ++q) L[q] = lp[q];

    // ---- decode all 8 entries first (issue all 16 gathers back-to-back) ----
    int   k0v[DBLOCK];
    float afv[DBLOCK], wv[DBLOCK];
#pragma unroll
    for (int q = 0; q < 4; ++q) {
#pragma unroll
        for (int h = 0; h < 2; ++h) {
            int   j  = q * 2 + h;
            float kf = h ? L[q].z : L[q].x;
            float af = h ? L[q].w : L[q].y;
            int k = (int)kf;
            bool valid = (unsigned)k < (unsigned)(NT - 1);
            k0v[j] = valid ? k : 0;
            afv[j] = af;
            wv[j]  = valid ? apod[j] : 0.0f;
        }
    }

    uint2 e0[DBLOCK], e1[DBLOCK];
#pragma unroll
    for (int j = 0; j < DBLOCK; ++j) {
        const uint2* row = ws16 + (size_t)(d0 + j) * NT;
        e0[j] = row[k0v[j]];
        e1[j] = row[k0v[j] + 1];
    }

    float acc[NB] = {0.0f, 0.0f, 0.0f, 0.0f};
#pragma unroll
    for (int j = 0; j < DBLOCK; ++j) {
        __half2 a01 = *(__half2*)&e0[j].x, a23 = *(__half2*)&e0[j].y;
        __half2 b01 = *(__half2*)&e1[j].x, b23 = *(__half2*)&e1[j].y;
        __half2 a2  = __float2half2_rn(afv[j]);
        __half2 s01 = __hfma2(a2, __hsub2(b01, a01), a01);
        __half2 s23 = __hfma2(a2, __hsub2(b23, a23), a23);
        float2 f01 = __half22float2(s01);
        float2 f23 = __half22float2(s23);
        acc[0] = fmaf(wv[j], f01.x, acc[0]);
        acc[1] = fmaf(wv[j], f01.y, acc[1]);
        acc[2] = fmaf(wv[j], f23.x, acc[2]);
        acc[3] = fmaf(wv[j], f23.y, acc[3]);
    }

    const float inv_norm = 1.0f / 63.5f;   // sum(apod) == 63.5 exactly
#pragma unroll
    for (int b = 0; b < NB; ++b)
        atomicAdd(&out[(size_t)b * NPIX + px], acc[b] * inv_norm);
}

// ---- fallback (ws too small): R8-style LDS kernel on raw sino ----
__global__ __launch_bounds__(512, 4)
void bp_fallback(const float* __restrict__ sino,
                 const float* __restrict__ lut,
                 float* __restrict__ out) {
    __shared__ __half2 lds[4][NT];
    const int tid   = threadIdx.x;
    const int octet = blockIdx.x & 15;
    const int tile  = blockIdx.x >> 4;
    const int d0    = octet * DBLOCK;
    const int px0   = tile * 1024;
    float apod[DBLOCK];
#pragma unroll
    for (int j = 0; j < DBLOCK; ++j) {
        float x = (float)(d0 + j) * (6.28318530717958647692f / 127.0f);
        apod[j] = 0.5f - 0.5f * __cosf(x);
    }
    float4 L[2][4];
#pragma unroll
    for (int i = 0; i < 2; ++i) {
        const float4* lq = (const float4*)
            (lut + ((size_t)(px0 + tid + i * 512) * NDET + d0) * 2);
#pragma unroll
        for (int q = 0; q < 4; ++q) L[i][q] = lq[q];
    }
    float acc[2][NB];
#pragma unroll
    for (int i = 0; i < 2; ++i)
#pragma unroll
        for (int b = 0; b < NB; ++b) acc[i][b] = 0.0f;
    const float4* s4 = (const float4*)sino;
    for (int ph = 0; ph < 4; ++ph) {
        const int b0  = (ph >> 1) * 2;
        const int dh  = ph & 1;
        const int dg0 = d0 + dh * 4;
        if (ph) __syncthreads();
        for (int f = tid; f < 4 * (NT / 4); f += 512) {
            int dl = f >> 9;
            int t4 = f & 511;
            size_t row = ((size_t)b0 * NDET + dg0 + dl) * (NT / 4) + t4;
            float4 ve = s4[row];
            float4 vo = s4[row + (size_t)NDET * (NT / 4)];
            __half2* dstp = &lds[dl][t4 * 4];
            dstp[0] = __floats2half2_rn(ve.x, vo.x);
            dstp[1] = __floats2half2_rn(ve.y, vo.y);
            dstp[2] = __floats2half2_rn(ve.z, vo.z);
            dstp[3] = __floats2half2_rn(ve.w, vo.w);
        }
        __syncthreads();
#pragma unroll
        for (int i = 0; i < 2; ++i) {
#pragma unroll
            for (int q2 = 0; q2 < 2; ++q2) {
                float4 Lq = L[i][dh * 2 + q2];
#pragma unroll
                for (int h = 0; h < 2; ++h) {
                    float kf = h ? Lq.z : Lq.x;
                    float af = h ? Lq.w : Lq.y;
                    int   dl = q2 * 2 + h;
                    int k = (int)kf;
                    bool valid = (unsigned)k < (unsigned)(NT - 1);
                    float w  = valid ? apod[dh * 4 + dl] : 0.0f;
                    int  k0  = valid ? k : 0;
                    __half2 s0v = lds[dl][k0];
                    __half2 s1v = lds[dl][k0 + 1];
                    __half2 a2  = __float2half2_rn(af);
                    __half2 sk  = __hfma2(a2, __hsub2(s1v, s0v), s0v);
                    float2  fv  = __half22float2(sk);
                    acc[i][b0 + 0] = fmaf(w, fv.x, acc[i][b0 + 0]);
                    acc[i][b0 + 1] = fmaf(w, fv.y, acc[i][b0 + 1]);
                }
            }
        }
    }
    const float inv_norm = 1.0f / 63.5f;
#pragma unroll
    for (int i = 0; i < 2; ++i) {
        const int px = px0 + tid + i * 512;
#pragma unroll
        for (int b = 0; b < NB; ++b)
            atomicAdd(&out[(size_t)b * NPIX + px], acc[i][b] * inv_norm);
    }
}

extern "C" void kernel_launch(void* const* d_in, const int* in_sizes, int n_in,
                              void* d_out, int out_size, void* d_ws, size_t ws_size,
                              hipStream_t stream) {
    const float* sino = (const float*)d_in[0];
    const float* lut  = (const float*)d_in[1];
    float* out = (float*)d_out;

    (void)hipMemsetAsync(d_out, 0, (size_t)out_size * sizeof(float), stream);

    const size_t ws_needed = (size_t)NDET * NT * sizeof(uint2);   // 2 MB
    if (ws_size >= ws_needed) {
        uint2* ws16 = (uint2*)d_ws;
        cvt_kernel<<<dim3(NDET * NT / 256), dim3(256), 0, stream>>>(sino, ws16);
        // 256 px-tiles x 16 octets = 4096 blocks x 256 thr, no LDS, no barriers
        bp_kernel<<<dim3(4096), dim3(THREADS), 0, stream>>>(ws16, lut, out);
    } else {
        bp_fallback<<<dim3(1024), dim3(512), 0, stream>>>(sino, lut, out);
    }
}

// Round 13
// 125.888 us; speedup vs baseline: 1.0194x; 1.0194x over previous
//
#include <hip/hip_runtime.h>
#include <hip/hip_fp16.h>

// BackProjectionLinear: out[b,p] = sum_d apod[d] * lerp(sino[b,d], k[p,d], a[p,d]) / 63.5
// B=4, N_DET=128, N_T=2048, pixels=65536.
//
// R13: the 43-49us invariant across R4..R12 (any phase/thread/LDS structure)
// is the lut HBM pattern: the octet split made every block read 64B per 1KB
// stride, so DRAM saw 16 uncorrelated 64B-granular streams -> ~1.9 TB/s
// random-access efficiency -> 85MB/1.9 = 45us. Fix: put all 16 octets of a
// pixel in ONE wave (lane = px_sub*16 + octet). Each wave's 4 lut loads
// fetch 4KB contiguous; waves advance sequentially -> dense stream at ~6TB/s.
//  - Bonus: per-pixel partials live in 16 lanes of one wave -> __shfl_xor
//    reduction replaces ALL atomics (and the out memset). WRITE 16.4->1.3MB.
//  - Gathers (R12): straight from L2 (ws16 = 2MB packed fp16, resident in
//    every XCD's 4MB L2). e0/e1 adjacent uint2 -> fusable to dwordx4.
//  - No LDS, no barriers; TLP/MLP hide latency.

#define NB      4
#define NDET    128
#define NT      2048
#define NPIX    65536
#define THREADS 256

// ---- pass 1: sino fp32[4][128][2048] -> ws16[det][t] = (h0,h1,h2,h3) 8B ----
__global__ __launch_bounds__(256)
void cvt_kernel(const float* __restrict__ sino, uint2* __restrict__ ws16) {
    const int id = blockIdx.x * 256 + threadIdx.x;     // det*NT + t
    float v0 = sino[id];
    float v1 = sino[id + NDET * NT];
    float v2 = sino[id + 2 * NDET * NT];
    float v3 = sino[id + 3 * NDET * NT];
    __half2 h01 = __floats2half2_rn(v0, v1);
    __half2 h23 = __floats2half2_rn(v2, v3);
    uint2 u;
    u.x = *(const unsigned*)&h01;
    u.y = *(const unsigned*)&h23;
    ws16[id] = u;
}

__global__ __launch_bounds__(THREADS, 4)
void bp_kernel(const uint2* __restrict__ ws16,
               const float* __restrict__ lut,
               float* __restrict__ out) {
    const int tid    = threadIdx.x;
    const int lane   = tid & 63;
    const int wid    = tid >> 6;          // wave in block: 0..3
    const int octet  = lane & 15;         // 16 octets of one pixel per wave
    const int px_sub = lane >> 4;         // 4 pixels per wave
    const int px     = blockIdx.x * 16 + wid * 4 + px_sub;
    const int d0     = octet * 8;

    float apod[8];
#pragma unroll
    for (int j = 0; j < 8; ++j) {
        float x = (float)(d0 + j) * (6.28318530717958647692f / 127.0f);
        apod[j] = 0.5f - 0.5f * __cosf(x);
    }

    // ---- lut: 4 float4/thread; wave covers 4KB CONTIGUOUS (sequential) ----
    // float4 index = px*64 + octet*4 + q
    const float4* lp = (const float4*)lut + ((size_t)px * 64 + octet * 4);
    float4 L[4];
#pragma unroll
    for (int q = 0; q < 4; ++q) L[q] = lp[q];

    // ---- gather 8 dets from L2-resident ws16 and accumulate 4 batches ----
    float acc[NB] = {0.0f, 0.0f, 0.0f, 0.0f};
#pragma unroll
    for (int q = 0; q < 4; ++q) {
#pragma unroll
        for (int h = 0; h < 2; ++h) {
            int   j  = q * 2 + h;
            float kf = h ? L[q].z : L[q].x;
            float af = h ? L[q].w : L[q].y;
            int k = (int)kf;
            bool valid = (unsigned)k < (unsigned)(NT - 1);
            float w  = valid ? apod[j] : 0.0f;
            int  k0  = valid ? k : 0;
            const uint2* row = ws16 + (size_t)(d0 + j) * NT + k0;
            uint2 e0 = row[0];            // t=k0  : 4 batches fp16
            uint2 e1 = row[1];            // t=k0+1: adjacent -> dwordx4 fuse
            __half2 a01 = *(__half2*)&e0.x, a23 = *(__half2*)&e0.y;
            __half2 b01 = *(__half2*)&e1.x, b23 = *(__half2*)&e1.y;
            __half2 a2  = __float2half2_rn(af);
            __half2 s01 = __hfma2(a2, __hsub2(b01, a01), a01);
            __half2 s23 = __hfma2(a2, __hsub2(b23, a23), a23);
            float2 f01 = __half22float2(s01);
            float2 f23 = __half22float2(s23);
            acc[0] = fmaf(w, f01.x, acc[0]);
            acc[1] = fmaf(w, f01.y, acc[1]);
            acc[2] = fmaf(w, f23.x, acc[2]);
            acc[3] = fmaf(w, f23.y, acc[3]);
        }
    }

    // ---- reduce the 16 octet-partials inside the wave (lanes differ in
    //      low 4 bits) -> no atomics, no memset ----
#pragma unroll
    for (int m = 1; m < 16; m <<= 1) {
#pragma unroll
        for (int b = 0; b < NB; ++b)
            acc[b] += __shfl_xor(acc[b], m, 64);
    }

    if (octet == 0) {
        const float inv_norm = 1.0f / 63.5f;   // sum(apod) == 63.5 exactly
#pragma unroll
        for (int b = 0; b < NB; ++b)
            out[(size_t)b * NPIX + px] = acc[b] * inv_norm;
    }
}

// ---- fallback (ws too small): R8-style LDS kernel on raw sino ----
__global__ __launch_bounds__(512, 4)
void bp_fallback(const float* __restrict__ sino,
                 const float* __restrict__ lut,
                 float* __restrict__ out) {
    __shared__ __half2 lds[4][NT];
    const int tid   = threadIdx.x;
    const int octet = blockIdx.x & 15;
    const int tile  = blockIdx.x >> 4;
    const int d0    = octet * 8;
    const int px0   = tile * 1024;
    float apod[8];
#pragma unroll
    for (int j = 0; j < 8; ++j) {
        float x = (float)(d0 + j) * (6.28318530717958647692f / 127.0f);
        apod[j] = 0.5f - 0.5f * __cosf(x);
    }
    float4 L[2][4];
#pragma unroll
    for (int i = 0; i < 2; ++i) {
        const float4* lq = (const float4*)
            (lut + ((size_t)(px0 + tid + i * 512) * NDET + d0) * 2);
#pragma unroll
        for (int q = 0; q < 4; ++q) L[i][q] = lq[q];
    }
    float acc[2][NB];
#pragma unroll
    for (int i = 0; i < 2; ++i)
#pragma unroll
        for (int b = 0; b < NB; ++b) acc[i][b] = 0.0f;
    const float4* s4 = (const float4*)sino;
    for (int ph = 0; ph < 4; ++ph) {
        const int b0  = (ph >> 1) * 2;
        const int dh  = ph & 1;
        const int dg0 = d0 + dh * 4;
        if (ph) __syncthreads();
        for (int f = tid; f < 4 * (NT / 4); f += 512) {
            int dl = f >> 9;
            int t4 = f & 511;
            size_t row = ((size_t)b0 * NDET + dg0 + dl) * (NT / 4) + t4;
            float4 ve = s4[row];
            float4 vo = s4[row + (size_t)NDET * (NT / 4)];
            __half2* dstp = &lds[dl][t4 * 4];
            dstp[0] = __floats2half2_rn(ve.x, vo.x);
            dstp[1] = __floats2half2_rn(ve.y, vo.y);
            dstp[2] = __floats2half2_rn(ve.z, vo.z);
            dstp[3] = __floats2half2_rn(ve.w, vo.w);
        }
        __syncthreads();
#pragma unroll
        for (int i = 0; i < 2; ++i) {
#pragma unroll
            for (int q2 = 0; q2 < 2; ++q2) {
                float4 Lq = L[i][dh * 2 + q2];
#pragma unroll
                for (int h = 0; h < 2; ++h) {
                    float kf = h ? Lq.z : Lq.x;
                    float af = h ? Lq.w : Lq.y;
                    int   dl = q2 * 2 + h;
                    int k = (int)kf;
                    bool valid = (unsigned)k < (unsigned)(NT - 1);
                    float w  = valid ? apod[dh * 4 + dl] : 0.0f;
                    int  k0  = valid ? k : 0;
                    __half2 s0v = lds[dl][k0];
                    __half2 s1v = lds[dl][k0 + 1];
                    __half2 a2  = __float2half2_rn(af);
                    __half2 sk  = __hfma2(a2, __hsub2(s1v, s0v), s0v);
                    float2  fv  = __half22float2(sk);
                    acc[i][b0 + 0] = fmaf(w, fv.x, acc[i][b0 + 0]);
                    acc[i][b0 + 1] = fmaf(w, fv.y, acc[i][b0 + 1]);
                }
            }
        }
    }
    const float inv_norm = 1.0f / 63.5f;
#pragma unroll
    for (int i = 0; i < 2; ++i) {
        const int px = px0 + tid + i * 512;
#pragma unroll
        for (int b = 0; b < NB; ++b)
            atomicAdd(&out[(size_t)b * NPIX + px], acc[i][b] * inv_norm);
    }
}

extern "C" void kernel_launch(void* const* d_in, const int* in_sizes, int n_in,
                              void* d_out, int out_size, void* d_ws, size_t ws_size,
                              hipStream_t stream) {
    const float* sino = (const float*)d_in[0];
    const float* lut  = (const float*)d_in[1];
    float* out = (float*)d_out;

    const size_t ws_needed = (size_t)NDET * NT * sizeof(uint2);   // 2 MB
    if (ws_size >= ws_needed) {
        uint2* ws16 = (uint2*)d_ws;
        cvt_kernel<<<dim3(NDET * NT / 256), dim3(256), 0, stream>>>(sino, ws16);
        // 4096 blocks x 256 thr; wave = 4 px x 16 octets; no LDS, no barriers,
        // no atomics (shfl reduce), every out element written exactly once.
        bp_kernel<<<dim3(NPIX / 16), dim3(THREADS), 0, stream>>>(ws16, lut, out);
    } else {
        (void)hipMemsetAsync(d_out, 0, (size_t)out_size * sizeof(float), stream);
        bp_fallback<<<dim3(1024), dim3(512), 0, stream>>>(sino, lut, out);
    }
}